// Round 1
// baseline (110.372 us; speedup 1.0000x reference)
//
#include <hip/hip_runtime.h>

#define D 256
#define S 128
#define B 32

typedef __attribute__((ext_vector_type(8))) short bf16x8;
typedef __attribute__((ext_vector_type(4))) float f32x4;

__device__ __forceinline__ unsigned short f2bf(float f) {
    union { float f; unsigned u; } v; v.f = f;
    unsigned r = v.u + 0x7FFFu + ((v.u >> 16) & 1u);   // RNE
    return (unsigned short)(r >> 16);
}
__device__ __forceinline__ float dot4(float4 a, float4 b) {
    return a.x * b.x + a.y * b.y + a.z * b.z + a.w * b.w;
}
__device__ __forceinline__ bf16x8 pack8(const float4 f0, const float4 f1) {
    union { unsigned short u[8]; bf16x8 v; } r;
    r.u[0] = f2bf(f0.x); r.u[1] = f2bf(f0.y); r.u[2] = f2bf(f0.z); r.u[3] = f2bf(f0.w);
    r.u[4] = f2bf(f1.x); r.u[5] = f2bf(f1.y); r.u[6] = f2bf(f1.z); r.u[7] = f2bf(f1.w);
    return r.v;
}

// K0: Wb[n][k] (bf16, 512x256) = n<256 ? Wl[n][k] : Wr[n-256][k].
__global__ __launch_bounds__(256) void k0_cast(
    const float* __restrict__ Wl, const float* __restrict__ Wr,
    unsigned short* __restrict__ Wb)
{
    const int idx = blockIdx.x * 256 + threadIdx.x;   // 32768 quads
    const int e = idx * 4;
    const int n = e >> 8, k = e & 255;
    const float* src = (n < 256) ? (Wl + (size_t)n * D + k)
                                 : (Wr + (size_t)(n - 256) * D + k);
    const float4 f = *(const float4*)src;
    ushort4 h;
    h.x = f2bf(f.x); h.y = f2bf(f.y); h.z = f2bf(f.z); h.w = f2bf(f.w);
    *(ushort4*)(Wb + (size_t)n * D + k) = h;
}

// K12 (fused MFMA + pairsum): one block per (b, dc-chunk of 16 d's).
// Phase 1: 128x32 GEMM slice (16 cols of Wl + 16 of Wr), A gathered from emb
//   in-register (fp32->bf16), B read bf16 from Wb in L2. fp32 acc + bias ->
//   padded LDS (stride 17, conflict-free).
// Phase 2: pooled[b,d] = 0.5*( S*(sum_j xl + sum_i xr) + sum_{ij}|xl_j+xr_i| )
//   with 8 independent |.| accumulator chains per thread.
// blockIdx decode: b = idx&31 so all 16 dc-blocks of one b sit on one XCD
//   (ids == b mod 8 under round-robin dispatch) -> emb re-gather is L2-local.
__global__ __launch_bounds__(256) void k12_fused(
    const int* __restrict__ X, const float* __restrict__ emb,
    const unsigned short* __restrict__ Wb,
    const float* __restrict__ bl, const float* __restrict__ br,
    float* __restrict__ pooled)
{
    constexpr int LP = 17;               // padded LDS row stride (floats)
    __shared__ float lxl[S * LP];        // 8704 B
    __shared__ float lxr[S * LP];        // 8704 B
    __shared__ float red[256];

    const int b   = blockIdx.x & 31;
    const int dc  = blockIdx.x >> 5;     // 0..15
    const int tid = threadIdx.x;
    const int w   = tid >> 6;            // wave 0..3
    const int l   = tid & 63;
    const int lm  = l & 15;
    const int lq  = l >> 4;

    // ---- Phase 1: GEMM. Wave w owns rows w*32..w*32+31 (2 row-tiles). ----
    const int r0 = w * 32 + lm;          // row-tile 0, m = lm
    const int tok0 = X[b * S + r0];
    const int tok1 = X[b * S + r0 + 16];
    const float* a0 = emb + (size_t)tok0 * D;
    const float* a1 = emb + (size_t)tok1 * D;
    // B fragments: row n = dc*16+lm of Wl (ct=0) / Wr (ct=1), k = lq*8 + ks*32.
    const unsigned short* bp_l = Wb + (size_t)(dc * 16 + lm) * D + lq * 8;
    const unsigned short* bp_r = bp_l + (size_t)256 * D;

    f32x4 acc[2][2];
#pragma unroll
    for (int rt = 0; rt < 2; ++rt)
#pragma unroll
        for (int ct = 0; ct < 2; ++ct)
            acc[rt][ct] = (f32x4){0.f, 0.f, 0.f, 0.f};

#pragma unroll
    for (int ks = 0; ks < 8; ++ks) {
        const int k0 = ks * 32 + lq * 8;
        const bf16x8 af0 = pack8(*(const float4*)(a0 + k0),
                                 *(const float4*)(a0 + k0 + 4));
        const bf16x8 af1 = pack8(*(const float4*)(a1 + k0),
                                 *(const float4*)(a1 + k0 + 4));
        const bf16x8 bf_l = *(const bf16x8*)(bp_l + ks * 32);
        const bf16x8 bf_r = *(const bf16x8*)(bp_r + ks * 32);
        acc[0][0] = __builtin_amdgcn_mfma_f32_16x16x32_bf16(af0, bf_l, acc[0][0], 0, 0, 0);
        acc[0][1] = __builtin_amdgcn_mfma_f32_16x16x32_bf16(af0, bf_r, acc[0][1], 0, 0, 0);
        acc[1][0] = __builtin_amdgcn_mfma_f32_16x16x32_bf16(af1, bf_l, acc[1][0], 0, 0, 0);
        acc[1][1] = __builtin_amdgcn_mfma_f32_16x16x32_bf16(af1, bf_r, acc[1][1], 0, 0, 0);
    }

    // Epilogue: C layout col=lane&15, row=(lane>>4)*4+i. fp32 + bias -> LDS.
    {
        const float bvl = bl[dc * 16 + lm];
        const float bvr = br[dc * 16 + lm];
#pragma unroll
        for (int rt = 0; rt < 2; ++rt) {
#pragma unroll
            for (int i = 0; i < 4; ++i) {
                const int row = w * 32 + rt * 16 + lq * 4 + i;
                lxl[row * LP + lm] = acc[rt][0][i] + bvl;
                lxr[row * LP + lm] = acc[rt][1][i] + bvr;
            }
        }
    }
    __syncthreads();

    // ---- Phase 2: pairsum over fp32 LDS. ----
    const int dl = tid & 15;
    const int ig = tid >> 4;             // 0..15, 8 i's each

    float xr[8];
    float sr = 0.f;
#pragma unroll
    for (int u = 0; u < 8; ++u) {
        xr[u] = lxr[(ig * 8 + u) * LP + dl];
        sr += xr[u];
    }

    float sa[8];
#pragma unroll
    for (int u = 0; u < 8; ++u) sa[u] = 0.f;
    float sxl = 0.f;
#pragma unroll 4
    for (int j = 0; j < S; ++j) {
        const float x = lxl[j * LP + dl];
        sxl += x;
#pragma unroll
        for (int u = 0; u < 8; ++u)
            sa[u] += fabsf(x + xr[u]);   // 8 independent chains
    }
    float sabs = ((sa[0] + sa[1]) + (sa[2] + sa[3]))
               + ((sa[4] + sa[5]) + (sa[6] + sa[7]));

    red[tid] = sabs + (float)S * sr;
    __syncthreads();

    if (tid < 16) {
        float tot = 0.f;
#pragma unroll
        for (int g = 0; g < 16; ++g) tot += red[g * 16 + tid];
        pooled[(size_t)b * D + (size_t)dc * 16 + tid] =
            0.5f * ((float)S * sxl + tot);
    }
}

// K3: out[b,d] = sum_k pooled[b,k]*Wrn[d,k] + S*S*brn[d]
__global__ __launch_bounds__(256) void k3_out(
    const float* __restrict__ pooled, const float* __restrict__ Wrn,
    const float* __restrict__ brn, float* __restrict__ out)
{
    __shared__ float lp[D];
    __shared__ float red[256];
    const int bb = blockIdx.x >> 3;
    const int dc = blockIdx.x & 7;
    const int tid = threadIdx.x;
    lp[tid] = pooled[(size_t)bb * D + tid];
    __syncthreads();

    const int dl = tid & 31;
    const int kg = tid >> 5;
    const int d = dc * 32 + dl;
    const float4* __restrict__ w4 = (const float4*)(Wrn + (size_t)d * D) + kg * 8;
    const float4* __restrict__ p4 = (const float4*)lp + kg * 8;
    float acc = 0.f;
#pragma unroll
    for (int f = 0; f < 8; ++f) acc += dot4(w4[f], p4[f]);

    red[tid] = acc;
    __syncthreads();
    if (tid < 32) {
        float s = 0.f;
#pragma unroll
        for (int g = 0; g < 8; ++g) s += red[g * 32 + tid];
        out[(size_t)bb * D + dc * 32 + tid] = s + (float)(S * S) * brn[dc * 32 + tid];
    }
}

extern "C" void kernel_launch(void* const* d_in, const int* in_sizes, int n_in,
                              void* d_out, int out_size, void* d_ws, size_t ws_size,
                              hipStream_t stream) {
    const int*   X   = (const int*)d_in[0];
    const float* emb = (const float*)d_in[1];
    const float* Wl  = (const float*)d_in[2];
    const float* bl  = (const float*)d_in[3];
    const float* Wr  = (const float*)d_in[4];
    const float* br  = (const float*)d_in[5];
    const float* Wrn = (const float*)d_in[6];
    const float* brn = (const float*)d_in[7];
    float* out = (float*)d_out;

    unsigned short* Wb = (unsigned short*)d_ws;            // 256 KB
    float* pooled = (float*)(Wb + (size_t)512 * D);        // 32 KB

    k0_cast<<<128, 256, 0, stream>>>(Wl, Wr, Wb);
    k12_fused<<<B * (D / 16), 256, 0, stream>>>(X, emb, Wb, bl, br, pooled);
    k3_out<<<B * 8, 256, 0, stream>>>(pooled, Wrn, brn, out);
}